// Round 1
// baseline (1175.270 us; speedup 1.0000x reference)
//
#include <hip/hip_runtime.h>
#include <math.h>

#define N_NODES 50000
#define E_EDGES 1200000
#define E_TOT   (E_EDGES + N_NODES)
#define NEG_SLOPE 0.2f
#define BN_EPS 1e-5f

// ---- monotone float <-> uint encoding for atomicMax on floats ----
__device__ __forceinline__ unsigned enc_f(float f) {
    unsigned u = __float_as_uint(f);
    return (u & 0x80000000u) ? ~u : (u | 0x80000000u);
}
__device__ __forceinline__ float dec_f(unsigned k) {
    unsigned u = (k & 0x80000000u) ? (k ^ 0x80000000u) : ~k;
    return __uint_as_float(u);
}

// ---- h = x @ W  (+ per-node attention coefficients) ----
// one wave (64 lanes) per node; lane = output channel; W staged in LDS.
template<int K>
__global__ void lin_att_kernel(const float* __restrict__ x,
                               const float* __restrict__ W,
                               const float* __restrict__ a_s,
                               const float* __restrict__ a_d,
                               float* __restrict__ h,
                               float* __restrict__ asrc,
                               float* __restrict__ adst,
                               int n) {
    __shared__ float sW[K * 64];
    __shared__ float sx[4][K];
    const int tid = threadIdx.x;
    const int wave = tid >> 6, lane = tid & 63;
    for (int i = tid; i < K * 64; i += 256) sW[i] = W[i];
    __syncthreads();
    const float a_sv = a_s[lane];   // [2][32] flattens exactly to lane
    const float a_dv = a_d[lane];
    const int ngroups = (n + 3) / 4;
    for (int g = blockIdx.x; g < ngroups; g += gridDim.x) {
        const int node = g * 4 + wave;
        if (node < n) {
            #pragma unroll
            for (int j = lane; j < K; j += 64) sx[wave][j] = x[node * K + j];
        }
        __syncthreads();
        if (node < n) {
            float acc = 0.f;
            #pragma unroll 8
            for (int k = 0; k < K; ++k) acc += sx[wave][k] * sW[k * 64 + lane];
            h[node * 64 + lane] = acc;
            float ps = acc * a_sv, pd = acc * a_dv;
            #pragma unroll
            for (int m = 1; m < 32; m <<= 1) {
                ps += __shfl_xor(ps, m, 64);
                pd += __shfl_xor(pd, m, 64);
            }
            if ((lane & 31) == 0) {
                asrc[node * 2 + (lane >> 5)] = ps;
                adst[node * 2 + (lane >> 5)] = pd;
            }
        }
        __syncthreads();
    }
}

// ---- pass 1: e = leaky_relu(asrc[s] + adst[d]); segment max into mkey ----
__global__ void edge_p1(const int* __restrict__ esrc, const int* __restrict__ edst,
                        const float2* __restrict__ asrc, const float2* __restrict__ adst,
                        float2* __restrict__ ebuf, unsigned* __restrict__ mkey) {
    int i = blockIdx.x * blockDim.x + threadIdx.x;
    if (i >= E_TOT) return;
    int s = (i < E_EDGES) ? esrc[i] : (i - E_EDGES);
    int d = (i < E_EDGES) ? edst[i] : (i - E_EDGES);
    float2 a = asrc[s], b = adst[d];
    float e0 = a.x + b.x; e0 = e0 > 0.f ? e0 : NEG_SLOPE * e0;
    float e1 = a.y + b.y; e1 = e1 > 0.f ? e1 : NEG_SLOPE * e1;
    ebuf[i] = make_float2(e0, e1);
    atomicMax(&mkey[d * 2 + 0], enc_f(e0));
    atomicMax(&mkey[d * 2 + 1], enc_f(e1));
}

// ---- pass 2: ee = exp(e - m[dst]); segment sum into denom ----
__global__ void edge_p2(const int* __restrict__ edst,
                        const unsigned* __restrict__ mkey,
                        float2* __restrict__ ebuf,
                        float* __restrict__ denom) {
    int i = blockIdx.x * blockDim.x + threadIdx.x;
    if (i >= E_TOT) return;
    int d = (i < E_EDGES) ? edst[i] : (i - E_EDGES);
    float2 e = ebuf[i];
    float ee0 = __expf(e.x - dec_f(mkey[d * 2 + 0]));
    float ee1 = __expf(e.y - dec_f(mkey[d * 2 + 1]));
    ebuf[i] = make_float2(ee0, ee1);
    atomicAdd(&denom[d * 2 + 0], ee0);
    atomicAdd(&denom[d * 2 + 1], ee1);
}

// ---- pass 3: acc[dst][c] += h[src][c] * alpha ; one wave per edge ----
__global__ void edge_p3(const int* __restrict__ esrc, const int* __restrict__ edst,
                        const float2* __restrict__ ebuf, const float2* __restrict__ denomv,
                        const float* __restrict__ h, float* __restrict__ acc) {
    int eidx = blockIdx.x * 4 + (threadIdx.x >> 6);
    int lane = threadIdx.x & 63;
    if (eidx >= E_TOT) return;
    int s = (eidx < E_EDGES) ? esrc[eidx] : (eidx - E_EDGES);
    int d = (eidx < E_EDGES) ? edst[eidx] : (eidx - E_EDGES);
    float2 ee = ebuf[eidx];
    float2 dn = denomv[d];
    float a0 = ee.x / (dn.x + 1e-16f);
    float a1 = ee.y / (dn.y + 1e-16f);
    float alpha = (lane < 32) ? a0 : a1;
    float hv = h[s * 64 + lane];
    atomicAdd(&acc[d * 64 + lane], hv * alpha);
}

// ---- bias + BN(eval) + ELU ----
__global__ void bn_elu_kernel(const float* __restrict__ acc, const float* __restrict__ b1,
                              const float* __restrict__ gamma, const float* __restrict__ beta,
                              const float* __restrict__ mean, const float* __restrict__ var,
                              float* __restrict__ x1) {
    int i = blockIdx.x * blockDim.x + threadIdx.x;
    if (i >= N_NODES * 64) return;
    int c = i & 63;
    float v = acc[i] + b1[c];
    v = (v - mean[c]) * rsqrtf(var[c] + BN_EPS) * gamma[c] + beta[c];
    x1[i] = v > 0.f ? v : (__expf(v) - 1.f);
}

// ---- JK max + final linear + log_softmax ; one wave per node ----
__global__ void final_kernel(const float* __restrict__ x1, const float* __restrict__ acc2,
                             const float* __restrict__ b2, const float* __restrict__ Wf,
                             const float* __restrict__ bf, float* __restrict__ out) {
    __shared__ float sWf[64 * 40 + 64];
    int tid = threadIdx.x, wave = tid >> 6, lane = tid & 63;
    for (int i = tid; i < 64 * 40; i += 256) sWf[i] = Wf[i];
    __syncthreads();
    int node = blockIdx.x * 4 + wave;
    if (node >= N_NODES) return;
    float jk = fmaxf(x1[node * 64 + lane], acc2[node * 64 + lane] + b2[lane]);
    const int o = (lane < 40) ? lane : 0;
    float acc = 0.f;
    #pragma unroll 8
    for (int c = 0; c < 64; ++c) {
        float jv = __shfl(jk, c, 64);
        acc += jv * sWf[c * 40 + o];
    }
    float logit = (lane < 40) ? (acc + bf[o]) : -INFINITY;
    float mx = logit;
    #pragma unroll
    for (int m = 1; m < 64; m <<= 1) mx = fmaxf(mx, __shfl_xor(mx, m, 64));
    float ex = (lane < 40) ? __expf(logit - mx) : 0.f;
    float sum = ex;
    #pragma unroll
    for (int m = 1; m < 64; m <<= 1) sum += __shfl_xor(sum, m, 64);
    if (lane < 40) out[node * 40 + lane] = logit - mx - logf(sum);
}

extern "C" void kernel_launch(void* const* d_in, const int* in_sizes, int n_in,
                              void* d_out, int out_size, void* d_ws, size_t ws_size,
                              hipStream_t stream) {
    const float* x     = (const float*)d_in[0];
    const int*   ei    = (const int*)d_in[1];
    const float* W1    = (const float*)d_in[2];
    const float* as1   = (const float*)d_in[3];
    const float* ad1   = (const float*)d_in[4];
    const float* b1    = (const float*)d_in[5];
    const float* gamma = (const float*)d_in[6];
    const float* beta  = (const float*)d_in[7];
    const float* mean  = (const float*)d_in[8];
    const float* var   = (const float*)d_in[9];
    const float* W2    = (const float*)d_in[10];
    const float* as2   = (const float*)d_in[11];
    const float* ad2   = (const float*)d_in[12];
    const float* b2    = (const float*)d_in[13];
    const float* Wf    = (const float*)d_in[14];
    const float* bf    = (const float*)d_in[15];
    float* out = (float*)d_out;
    const int* esrc = ei;
    const int* edst = ei + E_EDGES;

    char* ws = (char*)d_ws;
    size_t off = 0;
    auto alloc = [&](size_t bytes) {
        char* p = ws + off;
        off += (bytes + 255) & ~(size_t)255;
        return p;
    };
    // zero-region (acc, mkey, denom) must be contiguous & first
    float*    acc   = (float*)   alloc((size_t)N_NODES * 64 * 4);
    unsigned* mkey  = (unsigned*)alloc((size_t)N_NODES * 2 * 4);
    float*    denom = (float*)   alloc((size_t)N_NODES * 2 * 4);
    size_t zbytes = off;  // bytes to zero per layer
    float* hbuf  = (float*)alloc((size_t)N_NODES * 64 * 4);
    float* x1buf = (float*)alloc((size_t)N_NODES * 64 * 4);
    float* asrc  = (float*)alloc((size_t)N_NODES * 2 * 4);
    float* adst  = (float*)alloc((size_t)N_NODES * 2 * 4);
    float* ebuf  = (float*)alloc((size_t)E_TOT * 2 * 4);
    (void)ws_size; (void)in_sizes; (void)n_in; (void)out_size;

    const int EB = (E_TOT + 255) / 256;       // edge-parallel blocks
    const int EW = (E_TOT + 3) / 4;           // wave-per-edge blocks
    const int NB = (N_NODES + 3) / 4;         // wave-per-node blocks

    // ---------- layer 1 ----------
    hipMemsetAsync(acc, 0, zbytes, stream);
    lin_att_kernel<128><<<2048, 256, 0, stream>>>(x, W1, as1, ad1, hbuf, asrc, adst, N_NODES);
    edge_p1<<<EB, 256, 0, stream>>>(esrc, edst, (const float2*)asrc, (const float2*)adst,
                                    (float2*)ebuf, mkey);
    edge_p2<<<EB, 256, 0, stream>>>(edst, mkey, (float2*)ebuf, denom);
    edge_p3<<<EW, 256, 0, stream>>>(esrc, edst, (const float2*)ebuf, (const float2*)denom,
                                    hbuf, acc);
    bn_elu_kernel<<<(N_NODES * 64 + 255) / 256, 256, 0, stream>>>(acc, b1, gamma, beta,
                                                                  mean, var, x1buf);

    // ---------- layer 2 ----------
    hipMemsetAsync(acc, 0, zbytes, stream);
    lin_att_kernel<64><<<2048, 256, 0, stream>>>(x1buf, W2, as2, ad2, hbuf, asrc, adst, N_NODES);
    edge_p1<<<EB, 256, 0, stream>>>(esrc, edst, (const float2*)asrc, (const float2*)adst,
                                    (float2*)ebuf, mkey);
    edge_p2<<<EB, 256, 0, stream>>>(edst, mkey, (float2*)ebuf, denom);
    edge_p3<<<EW, 256, 0, stream>>>(esrc, edst, (const float2*)ebuf, (const float2*)denom,
                                    hbuf, acc);

    // ---------- JK + final linear + log_softmax ----------
    final_kernel<<<NB, 256, 0, stream>>>(x1buf, acc, b2, Wf, bf, out);
}

// Round 3
// 597.553 us; speedup vs baseline: 1.9668x; 1.9668x over previous
//
#include <hip/hip_runtime.h>
#include <math.h>

#define N_NODES 50000
#define E_EDGES 1200000
#define E_TOT   (E_EDGES + N_NODES)
#define NEG_SLOPE 0.2f
#define BN_EPS 1e-5f

// ==================== CSR build (once per call, reused by both layers) ====

__global__ void deg_kernel(const int* __restrict__ edst, int* __restrict__ deg) {
    int i = blockIdx.x * blockDim.x + threadIdx.x;
    if (i >= E_TOT) return;
    int d = (i < E_EDGES) ? edst[i] : (i - E_EDGES);
    atomicAdd(&deg[d], 1);
}

// single-workgroup exclusive scan of deg[0..N) -> ptr[0..N]
__global__ void scan_kernel(const int* __restrict__ deg, int* __restrict__ ptr) {
    __shared__ int lds[1024];
    const int t = threadIdx.x;
    const int C = (N_NODES + 1023) / 1024;
    const int beg = t * C;
    const int end = min(beg + C, N_NODES);
    int sum = 0;
    for (int i = beg; i < end; ++i) sum += deg[i];
    lds[t] = sum;
    __syncthreads();
    // Hillis-Steele inclusive scan over 1024 partials
    for (int off = 1; off < 1024; off <<= 1) {
        int x = (t >= off) ? lds[t - off] : 0;
        __syncthreads();
        lds[t] += x;
        __syncthreads();
    }
    int run = (t == 0) ? 0 : lds[t - 1];  // exclusive prefix
    for (int i = beg; i < end; ++i) { ptr[i] = run; run += deg[i]; }
    if (t == 1023) ptr[N_NODES] = run;    // = total (this thread covers no nodes)
}

__global__ void scatter_kernel(const int* __restrict__ esrc, const int* __restrict__ edst,
                               const int* __restrict__ ptr, int* __restrict__ cursor,
                               int* __restrict__ csr_src) {
    int i = blockIdx.x * blockDim.x + threadIdx.x;
    if (i >= E_TOT) return;
    int s = (i < E_EDGES) ? esrc[i] : (i - E_EDGES);
    int d = (i < E_EDGES) ? edst[i] : (i - E_EDGES);
    int slot = ptr[d] + atomicAdd(&cursor[d], 1);
    csr_src[slot] = s;
}

// ==================== h = x @ W  (+ attention coefficients) ==============
// one wave per node; lane = output channel; W staged in LDS.
template<int K>
__global__ void lin_att_kernel(const float* __restrict__ x,
                               const float* __restrict__ W,
                               const float* __restrict__ a_s,
                               const float* __restrict__ a_d,
                               float* __restrict__ h,
                               float* __restrict__ asrc,
                               float* __restrict__ adst,
                               int n) {
    __shared__ float sW[K * 64];
    __shared__ float sx[4][K];
    const int tid = threadIdx.x;
    const int wave = tid >> 6, lane = tid & 63;
    for (int i = tid; i < K * 64; i += 256) sW[i] = W[i];
    __syncthreads();
    const float a_sv = a_s[lane];   // [2][32] flattens exactly to lane
    const float a_dv = a_d[lane];
    const int ngroups = (n + 3) / 4;
    for (int g = blockIdx.x; g < ngroups; g += gridDim.x) {
        const int node = g * 4 + wave;
        if (node < n) {
            #pragma unroll
            for (int j = lane; j < K; j += 64) sx[wave][j] = x[node * K + j];
        }
        __syncthreads();
        if (node < n) {
            float acc = 0.f;
            #pragma unroll 8
            for (int k = 0; k < K; ++k) acc += sx[wave][k] * sW[k * 64 + lane];
            h[node * 64 + lane] = acc;
            float ps = acc * a_sv, pd = acc * a_dv;
            #pragma unroll
            for (int m = 1; m < 32; m <<= 1) {
                ps += __shfl_xor(ps, m, 64);
                pd += __shfl_xor(pd, m, 64);
            }
            if ((lane & 31) == 0) {
                asrc[node * 2 + (lane >> 5)] = ps;
                adst[node * 2 + (lane >> 5)] = pd;
            }
        }
        __syncthreads();
    }
}

// ==================== fused GAT aggregate: online softmax over CSR =======
// one wave per dst node; lane = channel (lanes 0-31 head0, 32-63 head1)
template<bool BN>
__global__ void gat_agg_kernel(const int* __restrict__ ptr, const int* __restrict__ csr_src,
                               const float* __restrict__ h,
                               const float2* __restrict__ asrc, const float2* __restrict__ adst,
                               const float* __restrict__ bias,
                               const float* __restrict__ gamma, const float* __restrict__ beta,
                               const float* __restrict__ mean, const float* __restrict__ var,
                               float* __restrict__ out) {
    int node = blockIdx.x * 4 + (threadIdx.x >> 6);
    if (node >= N_NODES) return;
    int lane = threadIdx.x & 63;
    float2 ad = adst[node];
    float adh = (lane < 32) ? ad.x : ad.y;
    float m = -INFINITY, s = 0.f, acc = 0.f;
    int e = ptr[node], end = ptr[node + 1];
    for (; e < end; ++e) {
        int src = csr_src[e];
        float2 as2 = asrc[src];
        float ev = ((lane < 32) ? as2.x : as2.y) + adh;
        ev = ev > 0.f ? ev : NEG_SLOPE * ev;
        float hv = h[src * 64 + lane];
        float mn = fmaxf(m, ev);
        float sc = __expf(m - mn);   // first iter: exp(-inf)=0
        float w  = __expf(ev - mn);
        s   = s * sc + w;
        acc = acc * sc + w * hv;
        m = mn;
    }
    float v = acc / (s + 1e-16f) + bias[lane];
    if (BN) {
        v = (v - mean[lane]) * rsqrtf(var[lane] + BN_EPS) * gamma[lane] + beta[lane];
        v = v > 0.f ? v : (__expf(v) - 1.f);   // ELU
    }
    out[node * 64 + lane] = v;
}

// ==================== JK max + final linear + log_softmax ================
__global__ void final_kernel(const float* __restrict__ x1, const float* __restrict__ x2,
                             const float* __restrict__ Wf, const float* __restrict__ bf,
                             float* __restrict__ out) {
    __shared__ float sWf[64 * 40 + 64];
    int tid = threadIdx.x, wave = tid >> 6, lane = tid & 63;
    for (int i = tid; i < 64 * 40; i += 256) sWf[i] = Wf[i];
    __syncthreads();
    int node = blockIdx.x * 4 + wave;
    if (node >= N_NODES) return;
    float jk = fmaxf(x1[node * 64 + lane], x2[node * 64 + lane]);
    const int o = (lane < 40) ? lane : 0;
    float acc = 0.f;
    #pragma unroll 8
    for (int c = 0; c < 64; ++c) {
        float jv = __shfl(jk, c, 64);
        acc += jv * sWf[c * 40 + o];
    }
    float logit = (lane < 40) ? (acc + bf[o]) : -INFINITY;
    float mx = logit;
    #pragma unroll
    for (int m = 1; m < 64; m <<= 1) mx = fmaxf(mx, __shfl_xor(mx, m, 64));
    float ex = (lane < 40) ? __expf(logit - mx) : 0.f;
    float sum = ex;
    #pragma unroll
    for (int m = 1; m < 64; m <<= 1) sum += __shfl_xor(sum, m, 64);
    if (lane < 40) out[node * 40 + lane] = logit - mx - logf(sum);
}

extern "C" void kernel_launch(void* const* d_in, const int* in_sizes, int n_in,
                              void* d_out, int out_size, void* d_ws, size_t ws_size,
                              hipStream_t stream) {
    const float* x     = (const float*)d_in[0];
    const int*   ei    = (const int*)d_in[1];
    const float* W1    = (const float*)d_in[2];
    const float* as1   = (const float*)d_in[3];
    const float* ad1   = (const float*)d_in[4];
    const float* b1    = (const float*)d_in[5];
    const float* gamma = (const float*)d_in[6];
    const float* beta  = (const float*)d_in[7];
    const float* mean  = (const float*)d_in[8];
    const float* var   = (const float*)d_in[9];
    const float* W2    = (const float*)d_in[10];
    const float* as2   = (const float*)d_in[11];
    const float* ad2   = (const float*)d_in[12];
    const float* b2    = (const float*)d_in[13];
    const float* Wf    = (const float*)d_in[14];
    const float* bf    = (const float*)d_in[15];
    float* out = (float*)d_out;
    const int* esrc = ei;
    const int* edst = ei + E_EDGES;

    char* ws = (char*)d_ws;
    size_t off = 0;
    auto alloc = [&](size_t bytes) {
        char* p = ws + off;
        off += (bytes + 255) & ~(size_t)255;
        return p;
    };
    // zero-region first (deg + cursor): one memset covers both
    int* deg    = (int*)alloc((size_t)N_NODES * 4);
    int* cursor = (int*)alloc((size_t)N_NODES * 4);
    size_t zbytes = off;
    int* ptr     = (int*)alloc((size_t)(N_NODES + 1) * 4);
    int* csr_src = (int*)alloc((size_t)E_TOT * 4);
    float* hbuf  = (float*)alloc((size_t)N_NODES * 64 * 4);
    float* x1buf = (float*)alloc((size_t)N_NODES * 64 * 4);
    float* x2buf = (float*)alloc((size_t)N_NODES * 64 * 4);
    float* asrc  = (float*)alloc((size_t)N_NODES * 2 * 4);
    float* adst  = (float*)alloc((size_t)N_NODES * 2 * 4);
    (void)ws_size; (void)in_sizes; (void)n_in; (void)out_size;

    const int EB = (E_TOT + 255) / 256;
    const int NB = (N_NODES + 3) / 4;

    // ---------- CSR build (by dst), shared by both layers ----------
    hipMemsetAsync(deg, 0, zbytes, stream);
    deg_kernel<<<EB, 256, 0, stream>>>(edst, deg);
    scan_kernel<<<1, 1024, 0, stream>>>(deg, ptr);
    scatter_kernel<<<EB, 256, 0, stream>>>(esrc, edst, ptr, cursor, csr_src);

    // ---------- layer 1 ----------
    lin_att_kernel<128><<<2048, 256, 0, stream>>>(x, W1, as1, ad1, hbuf, asrc, adst, N_NODES);
    gat_agg_kernel<true><<<NB, 256, 0, stream>>>(ptr, csr_src, hbuf,
                                                 (const float2*)asrc, (const float2*)adst,
                                                 b1, gamma, beta, mean, var, x1buf);

    // ---------- layer 2 ----------
    lin_att_kernel<64><<<2048, 256, 0, stream>>>(x1buf, W2, as2, ad2, hbuf, asrc, adst, N_NODES);
    gat_agg_kernel<false><<<NB, 256, 0, stream>>>(ptr, csr_src, hbuf,
                                                  (const float2*)asrc, (const float2*)adst,
                                                  b2, nullptr, nullptr, nullptr, nullptr, x2buf);

    // ---------- JK + final linear + log_softmax ----------
    final_kernel<<<NB, 256, 0, stream>>>(x1buf, x2buf, Wf, bf, out);
}

// Round 4
// 437.400 us; speedup vs baseline: 2.6869x; 1.3661x over previous
//
#include <hip/hip_runtime.h>
#include <math.h>

#define N_NODES 50000
#define E_EDGES 1200000
#define E_TOT   (E_EDGES + N_NODES)
#define NEG_SLOPE 0.2f
#define BN_EPS 1e-5f

// ==================== CSR build (once per call, reused by both layers) ====

__global__ void deg_kernel(const int* __restrict__ edst, int* __restrict__ deg) {
    int i = blockIdx.x * blockDim.x + threadIdx.x;
    if (i >= E_TOT) return;
    int d = (i < E_EDGES) ? edst[i] : (i - E_EDGES);
    atomicAdd(&deg[d], 1);
}

// single-workgroup exclusive scan of deg[0..N) -> ptr[0..N]
__global__ void scan_kernel(const int* __restrict__ deg, int* __restrict__ ptr) {
    __shared__ int lds[1024];
    const int t = threadIdx.x;
    const int C = (N_NODES + 1023) / 1024;
    const int beg = t * C;
    const int end = min(beg + C, N_NODES);
    int sum = 0;
    for (int i = beg; i < end; ++i) sum += deg[i];
    lds[t] = sum;
    __syncthreads();
    for (int off = 1; off < 1024; off <<= 1) {
        int x = (t >= off) ? lds[t - off] : 0;
        __syncthreads();
        lds[t] += x;
        __syncthreads();
    }
    int run = (t == 0) ? 0 : lds[t - 1];  // exclusive prefix
    for (int i = beg; i < end; ++i) { ptr[i] = run; run += deg[i]; }
    if (t == 1023) ptr[N_NODES] = run;
}

__global__ void scatter_kernel(const int* __restrict__ esrc, const int* __restrict__ edst,
                               const int* __restrict__ ptr, int* __restrict__ cursor,
                               int* __restrict__ csr_src) {
    int i = blockIdx.x * blockDim.x + threadIdx.x;
    if (i >= E_TOT) return;
    int s = (i < E_EDGES) ? esrc[i] : (i - E_EDGES);
    int d = (i < E_EDGES) ? edst[i] : (i - E_EDGES);
    int slot = ptr[d] + atomicAdd(&cursor[d], 1);
    csr_src[slot] = s;
}

// ==================== h = x @ W  (+ attention coefficients) ==============
template<int K>
__global__ void lin_att_kernel(const float* __restrict__ x,
                               const float* __restrict__ W,
                               const float* __restrict__ a_s,
                               const float* __restrict__ a_d,
                               float* __restrict__ h,
                               float* __restrict__ asrc,
                               float* __restrict__ adst,
                               int n) {
    __shared__ float sW[K * 64];
    __shared__ float sx[4][K];
    const int tid = threadIdx.x;
    const int wave = tid >> 6, lane = tid & 63;
    for (int i = tid; i < K * 64; i += 256) sW[i] = W[i];
    __syncthreads();
    const float a_sv = a_s[lane];
    const float a_dv = a_d[lane];
    const int ngroups = (n + 3) / 4;
    for (int g = blockIdx.x; g < ngroups; g += gridDim.x) {
        const int node = g * 4 + wave;
        if (node < n) {
            #pragma unroll
            for (int j = lane; j < K; j += 64) sx[wave][j] = x[node * K + j];
        }
        __syncthreads();
        if (node < n) {
            float acc = 0.f;
            #pragma unroll 8
            for (int k = 0; k < K; ++k) acc += sx[wave][k] * sW[k * 64 + lane];
            h[node * 64 + lane] = acc;
            float ps = acc * a_sv, pd = acc * a_dv;
            #pragma unroll
            for (int m = 1; m < 32; m <<= 1) {
                ps += __shfl_xor(ps, m, 64);
                pd += __shfl_xor(pd, m, 64);
            }
            if ((lane & 31) == 0) {
                asrc[node * 2 + (lane >> 5)] = ps;
                adst[node * 2 + (lane >> 5)] = pd;
            }
        }
        __syncthreads();
    }
}

// ==================== fused GAT aggregate: chunked flash-style ===========
// one wave per dst node; lane = channel (lanes 0-31 head0, 32-63 head1).
// Per chunk of 32 edges: lanes 0-31 each own one edge (index + asrc gather
// + e-value lane-parallel), shfl-reduce chunk max, rescale once, then a
// 4x-unrolled broadcast loop accumulates w_j * h[src_j][lane].
template<bool BN>
__global__ void gat_agg_kernel(const int* __restrict__ ptr, const int* __restrict__ csr_src,
                               const float* __restrict__ h,
                               const float2* __restrict__ asrc, const float2* __restrict__ adst,
                               const float* __restrict__ bias,
                               const float* __restrict__ gamma, const float* __restrict__ beta,
                               const float* __restrict__ mean, const float* __restrict__ var,
                               float* __restrict__ out) {
    int node = blockIdx.x * 4 + (threadIdx.x >> 6);
    if (node >= N_NODES) return;
    const int lane = threadIdx.x & 63;
    const int half = lane & 31;       // slot within 32-lane head group
    const int headsel = lane & 32;    // 0 for head0 lanes, 32 for head1 lanes
    float2 ad = adst[node];
    const float adh = (lane < 32) ? ad.x : ad.y;
    float m = -INFINITY, s = 0.f, acc = 0.f;
    const int beg = ptr[node], end = ptr[node + 1];
    for (int base = beg; base < end; base += 32) {
        const int cnt = min(32, end - base);
        int src = 0; float ev = -INFINITY;
        if (half < cnt) {
            src = csr_src[base + half];
            float2 a2 = asrc[src];
            ev = ((lane < 32) ? a2.x : a2.y) + adh;
            ev = ev > 0.f ? ev : NEG_SLOPE * ev;
        }
        // chunk max within each 32-lane half (xor<32 stays inside the half)
        float cmax = ev;
        #pragma unroll
        for (int o = 1; o < 32; o <<= 1) cmax = fmaxf(cmax, __shfl_xor(cmax, o, 64));
        const float mn = fmaxf(m, cmax);
        const float rescale = __expf(m - mn);   // first chunk: exp(-inf)=0
        const float w = (half < cnt) ? __expf(ev - mn) : 0.f;
        float ws = w;
        #pragma unroll
        for (int o = 1; o < 32; o <<= 1) ws += __shfl_xor(ws, o, 64);
        s = s * rescale + ws;
        acc *= rescale;
        m = mn;
        // broadcast loop: 4 independent h-row loads in flight
        int j = 0;
        for (; j + 4 <= cnt; j += 4) {
            int s0 = __shfl(src, j, 64);
            int s1 = __shfl(src, j + 1, 64);
            int s2 = __shfl(src, j + 2, 64);
            int s3 = __shfl(src, j + 3, 64);
            float w0 = __shfl(w, headsel + j, 64);
            float w1 = __shfl(w, headsel + j + 1, 64);
            float w2 = __shfl(w, headsel + j + 2, 64);
            float w3 = __shfl(w, headsel + j + 3, 64);
            float h0 = h[s0 * 64 + lane];
            float h1 = h[s1 * 64 + lane];
            float h2 = h[s2 * 64 + lane];
            float h3 = h[s3 * 64 + lane];
            acc += w0 * h0;
            acc += w1 * h1;
            acc += w2 * h2;
            acc += w3 * h3;
        }
        for (; j < cnt; ++j) {
            int sj = __shfl(src, j, 64);
            float wj = __shfl(w, headsel + j, 64);
            acc += wj * h[sj * 64 + lane];
        }
    }
    float v = acc / (s + 1e-16f) + bias[lane];
    if (BN) {
        v = (v - mean[lane]) * rsqrtf(var[lane] + BN_EPS) * gamma[lane] + beta[lane];
        v = v > 0.f ? v : (__expf(v) - 1.f);   // ELU
    }
    out[node * 64 + lane] = v;
}

// ==================== JK max + final linear + log_softmax ================
__global__ void final_kernel(const float* __restrict__ x1, const float* __restrict__ x2,
                             const float* __restrict__ Wf, const float* __restrict__ bf,
                             float* __restrict__ out) {
    __shared__ float sWf[64 * 40 + 64];
    int tid = threadIdx.x, wave = tid >> 6, lane = tid & 63;
    for (int i = tid; i < 64 * 40; i += 256) sWf[i] = Wf[i];
    __syncthreads();
    int node = blockIdx.x * 4 + wave;
    if (node >= N_NODES) return;
    float jk = fmaxf(x1[node * 64 + lane], x2[node * 64 + lane]);
    const int o = (lane < 40) ? lane : 0;
    float acc = 0.f;
    #pragma unroll 8
    for (int c = 0; c < 64; ++c) {
        float jv = __shfl(jk, c, 64);
        acc += jv * sWf[c * 40 + o];
    }
    float logit = (lane < 40) ? (acc + bf[o]) : -INFINITY;
    float mx = logit;
    #pragma unroll
    for (int m = 1; m < 64; m <<= 1) mx = fmaxf(mx, __shfl_xor(mx, m, 64));
    float ex = (lane < 40) ? __expf(logit - mx) : 0.f;
    float sum = ex;
    #pragma unroll
    for (int m = 1; m < 64; m <<= 1) sum += __shfl_xor(sum, m, 64);
    if (lane < 40) out[node * 40 + lane] = logit - mx - logf(sum);
}

extern "C" void kernel_launch(void* const* d_in, const int* in_sizes, int n_in,
                              void* d_out, int out_size, void* d_ws, size_t ws_size,
                              hipStream_t stream) {
    const float* x     = (const float*)d_in[0];
    const int*   ei    = (const int*)d_in[1];
    const float* W1    = (const float*)d_in[2];
    const float* as1   = (const float*)d_in[3];
    const float* ad1   = (const float*)d_in[4];
    const float* b1    = (const float*)d_in[5];
    const float* gamma = (const float*)d_in[6];
    const float* beta  = (const float*)d_in[7];
    const float* mean  = (const float*)d_in[8];
    const float* var   = (const float*)d_in[9];
    const float* W2    = (const float*)d_in[10];
    const float* as2   = (const float*)d_in[11];
    const float* ad2   = (const float*)d_in[12];
    const float* b2    = (const float*)d_in[13];
    const float* Wf    = (const float*)d_in[14];
    const float* bf    = (const float*)d_in[15];
    float* out = (float*)d_out;
    const int* esrc = ei;
    const int* edst = ei + E_EDGES;

    char* ws = (char*)d_ws;
    size_t off = 0;
    auto alloc = [&](size_t bytes) {
        char* p = ws + off;
        off += (bytes + 255) & ~(size_t)255;
        return p;
    };
    // zero-region first (deg + cursor): one memset covers both
    int* deg    = (int*)alloc((size_t)N_NODES * 4);
    int* cursor = (int*)alloc((size_t)N_NODES * 4);
    size_t zbytes = off;
    int* ptr     = (int*)alloc((size_t)(N_NODES + 1) * 4);
    int* csr_src = (int*)alloc((size_t)E_TOT * 4);
    float* hbuf  = (float*)alloc((size_t)N_NODES * 64 * 4);
    float* x1buf = (float*)alloc((size_t)N_NODES * 64 * 4);
    float* x2buf = (float*)alloc((size_t)N_NODES * 64 * 4);
    float* asrc  = (float*)alloc((size_t)N_NODES * 2 * 4);
    float* adst  = (float*)alloc((size_t)N_NODES * 2 * 4);
    (void)ws_size; (void)in_sizes; (void)n_in; (void)out_size;

    const int EB = (E_TOT + 255) / 256;
    const int NB = (N_NODES + 3) / 4;

    // ---------- CSR build (by dst), shared by both layers ----------
    hipMemsetAsync(deg, 0, zbytes, stream);
    deg_kernel<<<EB, 256, 0, stream>>>(edst, deg);
    scan_kernel<<<1, 1024, 0, stream>>>(deg, ptr);
    scatter_kernel<<<EB, 256, 0, stream>>>(esrc, edst, ptr, cursor, csr_src);

    // ---------- layer 1 ----------
    lin_att_kernel<128><<<2048, 256, 0, stream>>>(x, W1, as1, ad1, hbuf, asrc, adst, N_NODES);
    gat_agg_kernel<true><<<NB, 256, 0, stream>>>(ptr, csr_src, hbuf,
                                                 (const float2*)asrc, (const float2*)adst,
                                                 b1, gamma, beta, mean, var, x1buf);

    // ---------- layer 2 ----------
    lin_att_kernel<64><<<2048, 256, 0, stream>>>(x1buf, W2, as2, ad2, hbuf, asrc, adst, N_NODES);
    gat_agg_kernel<false><<<NB, 256, 0, stream>>>(ptr, csr_src, hbuf,
                                                  (const float2*)asrc, (const float2*)adst,
                                                  b2, nullptr, nullptr, nullptr, nullptr, x2buf);

    // ---------- JK + final linear + log_softmax ----------
    final_kernel<<<NB, 256, 0, stream>>>(x1buf, x2buf, Wf, bf, out);
}

// Round 6
// 424.545 us; speedup vs baseline: 2.7683x; 1.0303x over previous
//
#include <hip/hip_runtime.h>
#include <hip/hip_bf16.h>
#include <math.h>

#define N_NODES 50000
#define E_EDGES 1200000
#define E_TOT   (E_EDGES + N_NODES)
#define NEG_SLOPE 0.2f
#define BN_EPS 1e-5f

// ==================== CSR build (once per call, reused by both layers) ====

__global__ void deg_kernel(const int* __restrict__ edst, int* __restrict__ deg) {
    int i = blockIdx.x * blockDim.x + threadIdx.x;
    if (i >= E_TOT) return;
    int d = (i < E_EDGES) ? edst[i] : (i - E_EDGES);
    atomicAdd(&deg[d], 1);
}

// single-workgroup exclusive scan of deg[0..N) -> ptr[0..N]
__global__ void scan_kernel(const int* __restrict__ deg, int* __restrict__ ptr) {
    __shared__ int lds[1024];
    const int t = threadIdx.x;
    const int C = (N_NODES + 1023) / 1024;
    const int beg = t * C;
    const int end = min(beg + C, N_NODES);
    int sum = 0;
    for (int i = beg; i < end; ++i) sum += deg[i];
    lds[t] = sum;
    __syncthreads();
    for (int off = 1; off < 1024; off <<= 1) {
        int x = (t >= off) ? lds[t - off] : 0;
        __syncthreads();
        lds[t] += x;
        __syncthreads();
    }
    int run = (t == 0) ? 0 : lds[t - 1];  // exclusive prefix
    for (int i = beg; i < end; ++i) { ptr[i] = run; run += deg[i]; }
    if (t == 1023) ptr[N_NODES] = run;
}

// csr payload is u16 (src < 50000 < 2^16): 2.5 MB region stays L2-resident,
// dirty lines collect many stores before one byte-masked writeback.
__global__ void scatter_kernel(const int* __restrict__ esrc, const int* __restrict__ edst,
                               const int* __restrict__ ptr, int* __restrict__ cursor,
                               unsigned short* __restrict__ csr_src) {
    int i = blockIdx.x * blockDim.x + threadIdx.x;
    if (i >= E_TOT) return;
    int s = (i < E_EDGES) ? esrc[i] : (i - E_EDGES);
    int d = (i < E_EDGES) ? edst[i] : (i - E_EDGES);
    int slot = ptr[d] + atomicAdd(&cursor[d], 1);
    csr_src[slot] = (unsigned short)s;
}

// ==================== h = x @ W  (+ attention coefficients) ==============
// one wave per node; lane = output channel; W staged in LDS. h stored bf16.
template<int K>
__global__ void lin_att_kernel(const float* __restrict__ x,
                               const float* __restrict__ W,
                               const float* __restrict__ a_s,
                               const float* __restrict__ a_d,
                               __hip_bfloat16* __restrict__ h,
                               float* __restrict__ asrc,
                               float* __restrict__ adst,
                               int n) {
    __shared__ float sW[K * 64];
    __shared__ float sx[4][K];
    const int tid = threadIdx.x;
    const int wave = tid >> 6, lane = tid & 63;
    for (int i = tid; i < K * 64; i += 256) sW[i] = W[i];
    __syncthreads();
    const float a_sv = a_s[lane];
    const float a_dv = a_d[lane];
    const int ngroups = (n + 3) / 4;
    for (int g = blockIdx.x; g < ngroups; g += gridDim.x) {
        const int node = g * 4 + wave;
        if (node < n) {
            #pragma unroll
            for (int j = lane; j < K; j += 64) sx[wave][j] = x[node * K + j];
        }
        __syncthreads();
        if (node < n) {
            float acc = 0.f;
            #pragma unroll 8
            for (int k = 0; k < K; ++k) acc += sx[wave][k] * sW[k * 64 + lane];
            h[node * 64 + lane] = __float2bfloat16(acc);
            float ps = acc * a_sv, pd = acc * a_dv;
            #pragma unroll
            for (int m = 1; m < 32; m <<= 1) {
                ps += __shfl_xor(ps, m, 64);
                pd += __shfl_xor(pd, m, 64);
            }
            if ((lane & 31) == 0) {
                asrc[node * 2 + (lane >> 5)] = ps;
                adst[node * 2 + (lane >> 5)] = pd;
            }
        }
        __syncthreads();
    }
}

// ==================== fused GAT aggregate: chunked flash-style ===========
// one wave per dst node; lane = channel (lanes 0-31 head0, 32-63 head1).
// BN: apply bias+BN+ELU epilogue (layer 1).
// FINAL: fuse JK-max + final linear + log_softmax (layer 2) — no x2 write.
template<bool BN, bool FINAL>
__global__ void gat_agg_kernel(const int* __restrict__ ptr,
                               const unsigned short* __restrict__ csr_src,
                               const __hip_bfloat16* __restrict__ h,
                               const float2* __restrict__ asrc, const float2* __restrict__ adst,
                               const float* __restrict__ bias,
                               const float* __restrict__ gamma, const float* __restrict__ beta,
                               const float* __restrict__ mean, const float* __restrict__ var,
                               float* __restrict__ out,
                               const float* __restrict__ x1, const float* __restrict__ Wf,
                               const float* __restrict__ bf, float* __restrict__ out40) {
    __shared__ float sWf[FINAL ? 64 * 40 : 1];
    if constexpr (FINAL) {
        for (int i = threadIdx.x; i < 64 * 40; i += 256) sWf[i] = Wf[i];
        __syncthreads();
    }
    int node = blockIdx.x * 4 + (threadIdx.x >> 6);
    if (node >= N_NODES) return;
    const int lane = threadIdx.x & 63;
    const int half = lane & 31;
    const int headsel = lane & 32;
    float2 ad = adst[node];
    const float adh = (lane < 32) ? ad.x : ad.y;
    float m = -INFINITY, s = 0.f, acc = 0.f;
    const int beg = ptr[node], end = ptr[node + 1];
    for (int base = beg; base < end; base += 32) {
        const int cnt = min(32, end - base);
        int src = 0; float ev = -INFINITY;
        if (half < cnt) {
            src = (int)csr_src[base + half];
            float2 a2 = asrc[src];
            ev = ((lane < 32) ? a2.x : a2.y) + adh;
            ev = ev > 0.f ? ev : NEG_SLOPE * ev;
        }
        float cmax = ev;
        #pragma unroll
        for (int o = 1; o < 32; o <<= 1) cmax = fmaxf(cmax, __shfl_xor(cmax, o, 64));
        const float mn = fmaxf(m, cmax);
        const float rescale = __expf(m - mn);
        const float w = (half < cnt) ? __expf(ev - mn) : 0.f;
        float ws = w;
        #pragma unroll
        for (int o = 1; o < 32; o <<= 1) ws += __shfl_xor(ws, o, 64);
        s = s * rescale + ws;
        acc *= rescale;
        m = mn;
        int j = 0;
        for (; j + 4 <= cnt; j += 4) {
            int s0 = __shfl(src, j, 64);
            int s1 = __shfl(src, j + 1, 64);
            int s2 = __shfl(src, j + 2, 64);
            int s3 = __shfl(src, j + 3, 64);
            float w0 = __shfl(w, headsel + j, 64);
            float w1 = __shfl(w, headsel + j + 1, 64);
            float w2 = __shfl(w, headsel + j + 2, 64);
            float w3 = __shfl(w, headsel + j + 3, 64);
            float h0 = __bfloat162float(h[s0 * 64 + lane]);
            float h1 = __bfloat162float(h[s1 * 64 + lane]);
            float h2 = __bfloat162float(h[s2 * 64 + lane]);
            float h3 = __bfloat162float(h[s3 * 64 + lane]);
            acc += w0 * h0;
            acc += w1 * h1;
            acc += w2 * h2;
            acc += w3 * h3;
        }
        for (; j < cnt; ++j) {
            int sj = __shfl(src, j, 64);
            float wj = __shfl(w, headsel + j, 64);
            acc += wj * __bfloat162float(h[sj * 64 + lane]);
        }
    }
    float v = acc / (s + 1e-16f) + bias[lane];
    if constexpr (BN) {
        v = (v - mean[lane]) * rsqrtf(var[lane] + BN_EPS) * gamma[lane] + beta[lane];
        v = v > 0.f ? v : (__expf(v) - 1.f);   // ELU
    }
    if constexpr (FINAL) {
        float jk = fmaxf(x1[node * 64 + lane], v);
        const int o = (lane < 40) ? lane : 0;
        float dot = 0.f;
        #pragma unroll 8
        for (int c = 0; c < 64; ++c) {
            float jv = __shfl(jk, c, 64);
            dot += jv * sWf[c * 40 + o];
        }
        float logit = (lane < 40) ? (dot + bf[o]) : -INFINITY;
        float mx = logit;
        #pragma unroll
        for (int mm = 1; mm < 64; mm <<= 1) mx = fmaxf(mx, __shfl_xor(mx, mm, 64));
        float ex = (lane < 40) ? __expf(logit - mx) : 0.f;
        float sum = ex;
        #pragma unroll
        for (int mm = 1; mm < 64; mm <<= 1) sum += __shfl_xor(sum, mm, 64);
        if (lane < 40) out40[node * 40 + lane] = logit - mx - logf(sum);
    } else {
        out[node * 64 + lane] = v;
    }
}

extern "C" void kernel_launch(void* const* d_in, const int* in_sizes, int n_in,
                              void* d_out, int out_size, void* d_ws, size_t ws_size,
                              hipStream_t stream) {
    const float* x     = (const float*)d_in[0];
    const int*   ei    = (const int*)d_in[1];
    const float* W1    = (const float*)d_in[2];
    const float* as1   = (const float*)d_in[3];
    const float* ad1   = (const float*)d_in[4];
    const float* b1    = (const float*)d_in[5];
    const float* gamma = (const float*)d_in[6];
    const float* beta  = (const float*)d_in[7];
    const float* mean  = (const float*)d_in[8];
    const float* var   = (const float*)d_in[9];
    const float* W2    = (const float*)d_in[10];
    const float* as2   = (const float*)d_in[11];
    const float* ad2   = (const float*)d_in[12];
    const float* b2    = (const float*)d_in[13];
    const float* Wf    = (const float*)d_in[14];
    const float* bf    = (const float*)d_in[15];
    float* out = (float*)d_out;
    const int* esrc = ei;
    const int* edst = ei + E_EDGES;

    char* ws = (char*)d_ws;
    size_t off = 0;
    auto alloc = [&](size_t bytes) {
        char* p = ws + off;
        off += (bytes + 255) & ~(size_t)255;
        return p;
    };
    // zero-region first (deg + cursor): one memset covers both
    int* deg    = (int*)alloc((size_t)N_NODES * 4);
    int* cursor = (int*)alloc((size_t)N_NODES * 4);
    size_t zbytes = off;
    int* ptr             = (int*)alloc((size_t)(N_NODES + 1) * 4);
    unsigned short* csr  = (unsigned short*)alloc((size_t)E_TOT * 2);
    __hip_bfloat16* hbuf = (__hip_bfloat16*)alloc((size_t)N_NODES * 64 * 2);
    float* x1buf = (float*)alloc((size_t)N_NODES * 64 * 4);
    float* asrc  = (float*)alloc((size_t)N_NODES * 2 * 4);
    float* adst  = (float*)alloc((size_t)N_NODES * 2 * 4);
    (void)ws_size; (void)in_sizes; (void)n_in; (void)out_size;

    const int EB = (E_TOT + 255) / 256;
    const int NB = (N_NODES + 3) / 4;

    // ---------- CSR build (by dst), shared by both layers ----------
    hipMemsetAsync(deg, 0, zbytes, stream);
    deg_kernel<<<EB, 256, 0, stream>>>(edst, deg);
    scan_kernel<<<1, 1024, 0, stream>>>(deg, ptr);
    scatter_kernel<<<EB, 256, 0, stream>>>(esrc, edst, ptr, cursor, csr);

    // ---------- layer 1 ----------
    lin_att_kernel<128><<<2048, 256, 0, stream>>>(x, W1, as1, ad1, hbuf, asrc, adst, N_NODES);
    gat_agg_kernel<true, false><<<NB, 256, 0, stream>>>(ptr, csr, hbuf,
        (const float2*)asrc, (const float2*)adst,
        b1, gamma, beta, mean, var, x1buf, nullptr, nullptr, nullptr, nullptr);

    // ---------- layer 2 (+ fused JK + final linear + log_softmax) ----------
    lin_att_kernel<64><<<2048, 256, 0, stream>>>(x1buf, W2, as2, ad2, hbuf, asrc, adst, N_NODES);
    gat_agg_kernel<false, true><<<NB, 256, 0, stream>>>(ptr, csr, hbuf,
        (const float2*)asrc, (const float2*)adst,
        b2, nullptr, nullptr, nullptr, nullptr, nullptr, x1buf, Wf, bf, out);
}

// Round 10
// 412.977 us; speedup vs baseline: 2.8459x; 1.0280x over previous
//
#include <hip/hip_runtime.h>
#include <hip/hip_bf16.h>
#include <math.h>

#define N_NODES 50000
#define E_EDGES 1200000
#define E_TOT   (E_EDGES + N_NODES)
#define NEG_SLOPE 0.2f
#define BN_EPS 1e-5f

// wave-uniform lane broadcasts via v_readlane (SGPR path, no LDS/bpermute)
__device__ __forceinline__ int rl_i(int v, int l) {
    return __builtin_amdgcn_readlane(v, l);
}
__device__ __forceinline__ float rl_f(float v, int l) {
    return __uint_as_float(__builtin_amdgcn_readlane(__float_as_uint(v), l));
}

// ==================== CSR build (once per call, reused by both layers) ====

__global__ void deg_kernel(const int* __restrict__ edst, int* __restrict__ deg) {
    int i = blockIdx.x * blockDim.x + threadIdx.x;
    if (i >= E_TOT) return;
    int d = (i < E_EDGES) ? edst[i] : (i - E_EDGES);
    atomicAdd(&deg[d], 1);
}

// single-workgroup exclusive scan of deg[0..N) -> ptr[0..N]
__global__ void scan_kernel(const int* __restrict__ deg, int* __restrict__ ptr) {
    __shared__ int lds[1024];
    const int t = threadIdx.x;
    const int C = (N_NODES + 1023) / 1024;
    const int beg = t * C;
    const int end = min(beg + C, N_NODES);
    int sum = 0;
    for (int i = beg; i < end; ++i) sum += deg[i];
    lds[t] = sum;
    __syncthreads();
    for (int off = 1; off < 1024; off <<= 1) {
        int x = (t >= off) ? lds[t - off] : 0;
        __syncthreads();
        lds[t] += x;
        __syncthreads();
    }
    int run = (t == 0) ? 0 : lds[t - 1];  // exclusive prefix
    for (int i = beg; i < end; ++i) { ptr[i] = run; run += deg[i]; }
    if (t == 1023) ptr[N_NODES] = run;
}

// cursor is a D2D copy of ptr; one atomic gives the slot directly.
__global__ void scatter_kernel(const int* __restrict__ esrc, const int* __restrict__ edst,
                               int* __restrict__ cursor,
                               unsigned short* __restrict__ csr_src) {
    int i = blockIdx.x * blockDim.x + threadIdx.x;
    if (i >= E_TOT) return;
    int s = (i < E_EDGES) ? esrc[i] : (i - E_EDGES);
    int d = (i < E_EDGES) ? edst[i] : (i - E_EDGES);
    int slot = atomicAdd(&cursor[d], 1);
    csr_src[slot] = (unsigned short)s;
}

// ==================== h = x @ W  (+ attention coefficients) ==============
// one wave per node; lane = output channel; W in LDS; x-row in registers,
// broadcast via readlane (compile-time lane index) — no sx staging, no
// per-iteration __syncthreads.
template<int K>
__global__ void lin_att_kernel(const float* __restrict__ x,
                               const float* __restrict__ W,
                               const float* __restrict__ a_s,
                               const float* __restrict__ a_d,
                               __hip_bfloat16* __restrict__ h,
                               float* __restrict__ asrc,
                               float* __restrict__ adst,
                               int n) {
    __shared__ float sW[K * 64];
    const int tid = threadIdx.x, lane = tid & 63;
    for (int i = tid; i < K * 64; i += 256) sW[i] = W[i];
    __syncthreads();
    const float a_sv = a_s[lane];
    const float a_dv = a_d[lane];
    const int wid = blockIdx.x * 4 + (tid >> 6);
    const int nwaves = gridDim.x * 4;
    for (int node = wid; node < n; node += nwaves) {
        float xr[K / 64];
        #pragma unroll
        for (int p = 0; p < K / 64; ++p) xr[p] = x[node * K + p * 64 + lane];
        float acc = 0.f;
        #pragma unroll
        for (int p = 0; p < K / 64; ++p) {
            #pragma unroll
            for (int k = 0; k < 64; ++k) {
                float xk = rl_f(xr[p], k);           // v_readlane imm -> SGPR
                acc = fmaf(xk, sW[(p * 64 + k) * 64 + lane], acc);
            }
        }
        h[node * 64 + lane] = __float2bfloat16(acc);
        float ps = acc * a_sv, pd = acc * a_dv;
        #pragma unroll
        for (int m = 1; m < 32; m <<= 1) {
            ps += __shfl_xor(ps, m, 64);
            pd += __shfl_xor(pd, m, 64);
        }
        if ((lane & 31) == 0) {
            asrc[node * 2 + (lane >> 5)] = ps;
            adst[node * 2 + (lane >> 5)] = pd;
        }
    }
}

// ==================== fused GAT aggregate: chunked flash-style ===========
// one wave per dst node; lane = channel (lanes 0-31 head0, 32-63 head1).
// Broadcasts of (src, w) use readlane (SGPR), not ds_bpermute.
template<bool BN, bool FINAL>
__global__ void gat_agg_kernel(const int* __restrict__ ptr,
                               const unsigned short* __restrict__ csr_src,
                               const __hip_bfloat16* __restrict__ h,
                               const float2* __restrict__ asrc, const float2* __restrict__ adst,
                               const float* __restrict__ bias,
                               const float* __restrict__ gamma, const float* __restrict__ beta,
                               const float* __restrict__ mean, const float* __restrict__ var,
                               float* __restrict__ out,
                               const float* __restrict__ x1, const float* __restrict__ Wf,
                               const float* __restrict__ bf, float* __restrict__ out40) {
    __shared__ float sWf[FINAL ? 64 * 40 : 1];
    if constexpr (FINAL) {
        for (int i = threadIdx.x; i < 64 * 40; i += 256) sWf[i] = Wf[i];
        __syncthreads();
    }
    int node = blockIdx.x * 4 + (threadIdx.x >> 6);
    if (node >= N_NODES) return;
    const int lane = threadIdx.x & 63;
    const int half = lane & 31;
    float2 ad = adst[node];
    const float adh = (lane < 32) ? ad.x : ad.y;
    float m = -INFINITY, s = 0.f, acc = 0.f;
    const int beg = ptr[node], end = ptr[node + 1];
    for (int base = beg; base < end; base += 32) {
        const int cnt = min(32, end - base);
        int src = 0; float ev = -INFINITY;
        if (half < cnt) {
            src = (int)csr_src[base + half];
            float2 a2 = asrc[src];
            ev = ((lane < 32) ? a2.x : a2.y) + adh;
            ev = ev > 0.f ? ev : NEG_SLOPE * ev;
        }
        float cmax = ev;
        #pragma unroll
        for (int o = 1; o < 32; o <<= 1) cmax = fmaxf(cmax, __shfl_xor(cmax, o, 64));
        const float mn = fmaxf(m, cmax);
        const float rescale = __expf(m - mn);
        const float w = (half < cnt) ? __expf(ev - mn) : 0.f;
        float ws = w;
        #pragma unroll
        for (int o = 1; o < 32; o <<= 1) ws += __shfl_xor(ws, o, 64);
        s = s * rescale + ws;
        acc *= rescale;
        m = mn;
        int j = 0;
        for (; j + 4 <= cnt; j += 4) {
            int s0 = rl_i(src, j);
            int s1 = rl_i(src, j + 1);
            int s2 = rl_i(src, j + 2);
            int s3 = rl_i(src, j + 3);
            float wa0 = rl_f(w, j),      wb0 = rl_f(w, j + 32);
            float wa1 = rl_f(w, j + 1),  wb1 = rl_f(w, j + 33);
            float wa2 = rl_f(w, j + 2),  wb2 = rl_f(w, j + 34);
            float wa3 = rl_f(w, j + 3),  wb3 = rl_f(w, j + 35);
            float w0 = (lane < 32) ? wa0 : wb0;
            float w1 = (lane < 32) ? wa1 : wb1;
            float w2 = (lane < 32) ? wa2 : wb2;
            float w3 = (lane < 32) ? wa3 : wb3;
            float h0 = __bfloat162float(h[s0 * 64 + lane]);
            float h1 = __bfloat162float(h[s1 * 64 + lane]);
            float h2 = __bfloat162float(h[s2 * 64 + lane]);
            float h3 = __bfloat162float(h[s3 * 64 + lane]);
            acc = fmaf(w0, h0, acc);
            acc = fmaf(w1, h1, acc);
            acc = fmaf(w2, h2, acc);
            acc = fmaf(w3, h3, acc);
        }
        for (; j < cnt; ++j) {
            int sj = rl_i(src, j);
            float wa = rl_f(w, j), wb = rl_f(w, j + 32);
            float wj = (lane < 32) ? wa : wb;
            acc = fmaf(wj, __bfloat162float(h[sj * 64 + lane]), acc);
        }
    }
    float v = acc / (s + 1e-16f) + bias[lane];
    if constexpr (BN) {
        v = (v - mean[lane]) * rsqrtf(var[lane] + BN_EPS) * gamma[lane] + beta[lane];
        v = v > 0.f ? v : (__expf(v) - 1.f);   // ELU
    }
    if constexpr (FINAL) {
        float jk = fmaxf(x1[node * 64 + lane], v);
        const int o = (lane < 40) ? lane : 0;
        float dot = 0.f;
        #pragma unroll
        for (int c = 0; c < 64; ++c) {
            float jv = rl_f(jk, c);              // readlane imm -> SGPR
            dot = fmaf(jv, sWf[c * 40 + o], dot);
        }
        float logit = (lane < 40) ? (dot + bf[o]) : -INFINITY;
        float mx = logit;
        #pragma unroll
        for (int mm = 1; mm < 64; mm <<= 1) mx = fmaxf(mx, __shfl_xor(mx, mm, 64));
        float ex = (lane < 40) ? __expf(logit - mx) : 0.f;
        float sum = ex;
        #pragma unroll
        for (int mm = 1; mm < 64; mm <<= 1) sum += __shfl_xor(sum, mm, 64);
        if (lane < 40) out40[node * 40 + lane] = logit - mx - logf(sum);
    } else {
        out[node * 64 + lane] = v;
    }
}

extern "C" void kernel_launch(void* const* d_in, const int* in_sizes, int n_in,
                              void* d_out, int out_size, void* d_ws, size_t ws_size,
                              hipStream_t stream) {
    const float* x     = (const float*)d_in[0];
    const int*   ei    = (const int*)d_in[1];
    const float* W1    = (const float*)d_in[2];
    const float* as1   = (const float*)d_in[3];
    const float* ad1   = (const float*)d_in[4];
    const float* b1    = (const float*)d_in[5];
    const float* gamma = (const float*)d_in[6];
    const float* beta  = (const float*)d_in[7];
    const float* mean  = (const float*)d_in[8];
    const float* var   = (const float*)d_in[9];
    const float* W2    = (const float*)d_in[10];
    const float* as2   = (const float*)d_in[11];
    const float* ad2   = (const float*)d_in[12];
    const float* b2    = (const float*)d_in[13];
    const float* Wf    = (const float*)d_in[14];
    const float* bf    = (const float*)d_in[15];
    float* out = (float*)d_out;
    const int* esrc = ei;
    const int* edst = ei + E_EDGES;

    char* ws = (char*)d_ws;
    size_t off = 0;
    auto alloc = [&](size_t bytes) {
        char* p = ws + off;
        off += (bytes + 255) & ~(size_t)255;
        return p;
    };
    int* deg    = (int*)alloc((size_t)N_NODES * 4);     // zeroed each call
    size_t zbytes = off;
    int* cursor = (int*)alloc((size_t)N_NODES * 4);     // D2D copy of ptr
    int* ptr             = (int*)alloc((size_t)(N_NODES + 1) * 4);
    unsigned short* csr  = (unsigned short*)alloc((size_t)E_TOT * 2);
    __hip_bfloat16* hbuf = (__hip_bfloat16*)alloc((size_t)N_NODES * 64 * 2);
    float* x1buf = (float*)alloc((size_t)N_NODES * 64 * 4);
    float* asrc  = (float*)alloc((size_t)N_NODES * 2 * 4);
    float* adst  = (float*)alloc((size_t)N_NODES * 2 * 4);
    (void)ws_size; (void)in_sizes; (void)n_in; (void)out_size;

    const int EB = (E_TOT + 255) / 256;
    const int NB = (N_NODES + 3) / 4;

    // ---------- CSR build (by dst), shared by both layers ----------
    hipMemsetAsync(deg, 0, zbytes, stream);
    deg_kernel<<<EB, 256, 0, stream>>>(edst, deg);
    scan_kernel<<<1, 1024, 0, stream>>>(deg, ptr);
    hipMemcpyAsync(cursor, ptr, (size_t)N_NODES * 4, hipMemcpyDeviceToDevice, stream);
    scatter_kernel<<<EB, 256, 0, stream>>>(esrc, edst, cursor, csr);

    // ---------- layer 1 ----------
    lin_att_kernel<128><<<2048, 256, 0, stream>>>(x, W1, as1, ad1, hbuf, asrc, adst, N_NODES);
    gat_agg_kernel<true, false><<<NB, 256, 0, stream>>>(ptr, csr, hbuf,
        (const float2*)asrc, (const float2*)adst,
        b1, gamma, beta, mean, var, x1buf, nullptr, nullptr, nullptr, nullptr);

    // ---------- layer 2 (+ fused JK + final linear + log_softmax) ----------
    lin_att_kernel<64><<<2048, 256, 0, stream>>>(x1buf, W2, as2, ad2, hbuf, asrc, adst, N_NODES);
    gat_agg_kernel<false, true><<<NB, 256, 0, stream>>>(ptr, csr, hbuf,
        (const float2*)asrc, (const float2*)adst,
        b2, nullptr, nullptr, nullptr, nullptr, nullptr, x1buf, Wf, bf, out);
}

// Round 11
// 412.343 us; speedup vs baseline: 2.8502x; 1.0015x over previous
//
#include <hip/hip_runtime.h>
#include <hip/hip_bf16.h>
#include <math.h>

#define N_NODES 50000
#define E_EDGES 1200000
#define E_TOT   (E_EDGES + N_NODES)
#define NEG_SLOPE 0.2f
#define BN_EPS 1e-5f

// wave-uniform lane broadcasts via v_readlane (SGPR path, no LDS/bpermute)
__device__ __forceinline__ int rl_i(int v, int l) {
    return __builtin_amdgcn_readlane(v, l);
}
__device__ __forceinline__ float rl_f(float v, int l) {
    return __uint_as_float(__builtin_amdgcn_readlane(__float_as_uint(v), l));
}

// ==================== CSR build via linked list (one writer per region) ===

// per edge: push onto dst's list (coalesced 8B store), bump degree.
__global__ void link_kernel(const int* __restrict__ esrc, const int* __restrict__ edst,
                            int* __restrict__ head, int* __restrict__ deg,
                            uint2* __restrict__ link) {
    int i = blockIdx.x * blockDim.x + threadIdx.x;
    if (i >= E_TOT) return;
    int s = (i < E_EDGES) ? esrc[i] : (i - E_EDGES);
    int d = (i < E_EDGES) ? edst[i] : (i - E_EDGES);
    int old = atomicExch(&head[d], i);
    atomicAdd(&deg[d], 1);
    link[i] = make_uint2((unsigned)old, (unsigned)s);
}

// single-workgroup exclusive scan of deg[0..N) -> ptr[0..N]
__global__ void scan_kernel(const int* __restrict__ deg, int* __restrict__ ptr) {
    __shared__ int lds[1024];
    const int t = threadIdx.x;
    const int C = (N_NODES + 1023) / 1024;
    const int beg = t * C;
    const int end = min(beg + C, N_NODES);
    int sum = 0;
    for (int i = beg; i < end; ++i) sum += deg[i];
    lds[t] = sum;
    __syncthreads();
    for (int off = 1; off < 1024; off <<= 1) {
        int x = (t >= off) ? lds[t - off] : 0;
        __syncthreads();
        lds[t] += x;
        __syncthreads();
    }
    int run = (t == 0) ? 0 : lds[t - 1];  // exclusive prefix
    for (int i = beg; i < end; ++i) { ptr[i] = run; run += deg[i]; }
    if (t == 1023) ptr[N_NODES] = run;
}

// one THREAD per node: walk the chain, write csr region sequentially.
// A wave's 64 lanes own 64 consecutive nodes -> contiguous write window,
// single-XCD ownership, no cross-XCD line bounce.
__global__ void walk_kernel(const int* __restrict__ head, const int* __restrict__ ptr,
                            const uint2* __restrict__ link,
                            unsigned short* __restrict__ csr) {
    int d = blockIdx.x * blockDim.x + threadIdx.x;
    if (d >= N_NODES) return;
    int p = ptr[d];
    int cur = head[d];
    while (cur >= 0) {
        uint2 ls = link[cur];
        csr[p++] = (unsigned short)ls.y;
        cur = (int)ls.x;
    }
}

// ==================== h = x @ W  (+ attention coefficients) ==============
// one wave per node; lane = output channel; W in LDS; x-row in registers,
// broadcast via readlane (compile-time lane index).
template<int K>
__global__ void lin_att_kernel(const float* __restrict__ x,
                               const float* __restrict__ W,
                               const float* __restrict__ a_s,
                               const float* __restrict__ a_d,
                               __hip_bfloat16* __restrict__ h,
                               float* __restrict__ asrc,
                               float* __restrict__ adst,
                               int n) {
    __shared__ float sW[K * 64];
    const int tid = threadIdx.x, lane = tid & 63;
    for (int i = tid; i < K * 64; i += 256) sW[i] = W[i];
    __syncthreads();
    const float a_sv = a_s[lane];
    const float a_dv = a_d[lane];
    const int wid = blockIdx.x * 4 + (tid >> 6);
    const int nwaves = gridDim.x * 4;
    for (int node = wid; node < n; node += nwaves) {
        float xr[K / 64];
        #pragma unroll
        for (int p = 0; p < K / 64; ++p) xr[p] = x[node * K + p * 64 + lane];
        float acc = 0.f;
        #pragma unroll
        for (int p = 0; p < K / 64; ++p) {
            #pragma unroll
            for (int k = 0; k < 64; ++k) {
                float xk = rl_f(xr[p], k);           // v_readlane imm -> SGPR
                acc = fmaf(xk, sW[(p * 64 + k) * 64 + lane], acc);
            }
        }
        h[node * 64 + lane] = __float2bfloat16(acc);
        float ps = acc * a_sv, pd = acc * a_dv;
        #pragma unroll
        for (int m = 1; m < 32; m <<= 1) {
            ps += __shfl_xor(ps, m, 64);
            pd += __shfl_xor(pd, m, 64);
        }
        if ((lane & 31) == 0) {
            asrc[node * 2 + (lane >> 5)] = ps;
            adst[node * 2 + (lane >> 5)] = pd;
        }
    }
}

// ==================== fused GAT aggregate: chunked flash-style ===========
// one wave per dst node; lane = channel (lanes 0-31 head0, 32-63 head1).
// Broadcasts of (src, w) use readlane (SGPR), not ds_bpermute.
template<bool BN, bool FINAL>
__global__ void gat_agg_kernel(const int* __restrict__ ptr,
                               const unsigned short* __restrict__ csr_src,
                               const __hip_bfloat16* __restrict__ h,
                               const float2* __restrict__ asrc, const float2* __restrict__ adst,
                               const float* __restrict__ bias,
                               const float* __restrict__ gamma, const float* __restrict__ beta,
                               const float* __restrict__ mean, const float* __restrict__ var,
                               float* __restrict__ out,
                               const float* __restrict__ x1, const float* __restrict__ Wf,
                               const float* __restrict__ bf, float* __restrict__ out40) {
    __shared__ float sWf[FINAL ? 64 * 40 : 1];
    if constexpr (FINAL) {
        for (int i = threadIdx.x; i < 64 * 40; i += 256) sWf[i] = Wf[i];
        __syncthreads();
    }
    int node = blockIdx.x * 4 + (threadIdx.x >> 6);
    if (node >= N_NODES) return;
    const int lane = threadIdx.x & 63;
    const int half = lane & 31;
    float2 ad = adst[node];
    const float adh = (lane < 32) ? ad.x : ad.y;
    float m = -INFINITY, s = 0.f, acc = 0.f;
    const int beg = ptr[node], end = ptr[node + 1];
    for (int base = beg; base < end; base += 32) {
        const int cnt = min(32, end - base);
        int src = 0; float ev = -INFINITY;
        if (half < cnt) {
            src = (int)csr_src[base + half];
            float2 a2 = asrc[src];
            ev = ((lane < 32) ? a2.x : a2.y) + adh;
            ev = ev > 0.f ? ev : NEG_SLOPE * ev;
        }
        float cmax = ev;
        #pragma unroll
        for (int o = 1; o < 32; o <<= 1) cmax = fmaxf(cmax, __shfl_xor(cmax, o, 64));
        const float mn = fmaxf(m, cmax);
        const float rescale = __expf(m - mn);
        const float w = (half < cnt) ? __expf(ev - mn) : 0.f;
        float ws = w;
        #pragma unroll
        for (int o = 1; o < 32; o <<= 1) ws += __shfl_xor(ws, o, 64);
        s = s * rescale + ws;
        acc *= rescale;
        m = mn;
        int j = 0;
        for (; j + 4 <= cnt; j += 4) {
            int s0 = rl_i(src, j);
            int s1 = rl_i(src, j + 1);
            int s2 = rl_i(src, j + 2);
            int s3 = rl_i(src, j + 3);
            float wa0 = rl_f(w, j),      wb0 = rl_f(w, j + 32);
            float wa1 = rl_f(w, j + 1),  wb1 = rl_f(w, j + 33);
            float wa2 = rl_f(w, j + 2),  wb2 = rl_f(w, j + 34);
            float wa3 = rl_f(w, j + 3),  wb3 = rl_f(w, j + 35);
            float w0 = (lane < 32) ? wa0 : wb0;
            float w1 = (lane < 32) ? wa1 : wb1;
            float w2 = (lane < 32) ? wa2 : wb2;
            float w3 = (lane < 32) ? wa3 : wb3;
            float h0 = __bfloat162float(h[s0 * 64 + lane]);
            float h1 = __bfloat162float(h[s1 * 64 + lane]);
            float h2 = __bfloat162float(h[s2 * 64 + lane]);
            float h3 = __bfloat162float(h[s3 * 64 + lane]);
            acc = fmaf(w0, h0, acc);
            acc = fmaf(w1, h1, acc);
            acc = fmaf(w2, h2, acc);
            acc = fmaf(w3, h3, acc);
        }
        for (; j < cnt; ++j) {
            int sj = rl_i(src, j);
            float wa = rl_f(w, j), wb = rl_f(w, j + 32);
            float wj = (lane < 32) ? wa : wb;
            acc = fmaf(wj, __bfloat162float(h[sj * 64 + lane]), acc);
        }
    }
    float v = acc / (s + 1e-16f) + bias[lane];
    if constexpr (BN) {
        v = (v - mean[lane]) * rsqrtf(var[lane] + BN_EPS) * gamma[lane] + beta[lane];
        v = v > 0.f ? v : (__expf(v) - 1.f);   // ELU
    }
    if constexpr (FINAL) {
        float jk = fmaxf(x1[node * 64 + lane], v);
        const int o = (lane < 40) ? lane : 0;
        float dot = 0.f;
        #pragma unroll
        for (int c = 0; c < 64; ++c) {
            float jv = rl_f(jk, c);              // readlane imm -> SGPR
            dot = fmaf(jv, sWf[c * 40 + o], dot);
        }
        float logit = (lane < 40) ? (dot + bf[o]) : -INFINITY;
        float mx = logit;
        #pragma unroll
        for (int mm = 1; mm < 64; mm <<= 1) mx = fmaxf(mx, __shfl_xor(mx, mm, 64));
        float ex = (lane < 40) ? __expf(logit - mx) : 0.f;
        float sum = ex;
        #pragma unroll
        for (int mm = 1; mm < 64; mm <<= 1) sum += __shfl_xor(sum, mm, 64);
        if (lane < 40) out40[node * 40 + lane] = logit - mx - logf(sum);
    } else {
        out[node * 64 + lane] = v;
    }
}

extern "C" void kernel_launch(void* const* d_in, const int* in_sizes, int n_in,
                              void* d_out, int out_size, void* d_ws, size_t ws_size,
                              hipStream_t stream) {
    const float* x     = (const float*)d_in[0];
    const int*   ei    = (const int*)d_in[1];
    const float* W1    = (const float*)d_in[2];
    const float* as1   = (const float*)d_in[3];
    const float* ad1   = (const float*)d_in[4];
    const float* b1    = (const float*)d_in[5];
    const float* gamma = (const float*)d_in[6];
    const float* beta  = (const float*)d_in[7];
    const float* mean  = (const float*)d_in[8];
    const float* var   = (const float*)d_in[9];
    const float* W2    = (const float*)d_in[10];
    const float* as2   = (const float*)d_in[11];
    const float* ad2   = (const float*)d_in[12];
    const float* b2    = (const float*)d_in[13];
    const float* Wf    = (const float*)d_in[14];
    const float* bf    = (const float*)d_in[15];
    float* out = (float*)d_out;
    const int* esrc = ei;
    const int* edst = ei + E_EDGES;

    char* ws = (char*)d_ws;
    size_t off = 0;
    auto alloc = [&](size_t bytes) {
        char* p = ws + off;
        off += (bytes + 255) & ~(size_t)255;
        return p;
    };
    int* deg    = (int*)alloc((size_t)N_NODES * 4);     // memset 0x00
    size_t zbytes = off;
    int* head   = (int*)alloc((size_t)N_NODES * 4);     // memset 0xFF (-1)
    size_t hbytes = off - zbytes;
    int* ptr             = (int*)alloc((size_t)(N_NODES + 1) * 4);
    uint2* link          = (uint2*)alloc((size_t)E_TOT * 8);
    unsigned short* csr  = (unsigned short*)alloc((size_t)E_TOT * 2);
    __hip_bfloat16* hbuf = (__hip_bfloat16*)alloc((size_t)N_NODES * 64 * 2);
    float* x1buf = (float*)alloc((size_t)N_NODES * 64 * 4);
    float* asrc  = (float*)alloc((size_t)N_NODES * 2 * 4);
    float* adst  = (float*)alloc((size_t)N_NODES * 2 * 4);
    (void)ws_size; (void)in_sizes; (void)n_in; (void)out_size;

    const int EB = (E_TOT + 255) / 256;
    const int NB = (N_NODES + 3) / 4;
    const int TB = (N_NODES + 255) / 256;   // thread-per-node blocks

    // ---------- CSR build (by dst), shared by both layers ----------
    hipMemsetAsync(deg, 0, zbytes, stream);
    hipMemsetAsync(head, 0xFF, hbytes, stream);
    link_kernel<<<EB, 256, 0, stream>>>(esrc, edst, head, deg, link);
    scan_kernel<<<1, 1024, 0, stream>>>(deg, ptr);
    walk_kernel<<<TB, 256, 0, stream>>>(head, ptr, link, csr);

    // ---------- layer 1 ----------
    lin_att_kernel<128><<<2048, 256, 0, stream>>>(x, W1, as1, ad1, hbuf, asrc, adst, N_NODES);
    gat_agg_kernel<true, false><<<NB, 256, 0, stream>>>(ptr, csr, hbuf,
        (const float2*)asrc, (const float2*)adst,
        b1, gamma, beta, mean, var, x1buf, nullptr, nullptr, nullptr, nullptr);

    // ---------- layer 2 (+ fused JK + final linear + log_softmax) ----------
    lin_att_kernel<64><<<2048, 256, 0, stream>>>(x1buf, W2, as2, ad2, hbuf, asrc, adst, N_NODES);
    gat_agg_kernel<false, true><<<NB, 256, 0, stream>>>(ptr, csr, hbuf,
        (const float2*)asrc, (const float2*)adst,
        b2, nullptr, nullptr, nullptr, nullptr, nullptr, x1buf, Wf, bf, out);
}

// Round 12
// 256.006 us; speedup vs baseline: 4.5908x; 1.6107x over previous
//
#include <hip/hip_runtime.h>
#include <hip/hip_bf16.h>
#include <math.h>

#define N_NODES 50000
#define E_EDGES 1200000
#define E_TOT   (E_EDGES + N_NODES)
#define NEG_SLOPE 0.2f
#define BN_EPS 1e-5f
#define P_PART 196          // partitions of 256 nodes (dst >> 8)
#define B1 256              // blocks in hist/scatter passes
#define NSCAN (P_PART * B1) // 50176

// wave-uniform lane broadcasts via v_readlane (SGPR path, no LDS/bpermute)
__device__ __forceinline__ int rl_i(int v, int l) {
    return __builtin_amdgcn_readlane(v, l);
}
__device__ __forceinline__ float rl_f(float v, int l) {
    return __uint_as_float(__builtin_amdgcn_readlane(__float_as_uint(v), l));
}

// ==================== atomic-free CSR build (partition sort) =============
// Pass 1: per-block LDS histogram of dst partitions.
__global__ void hist_kernel(const int* __restrict__ edst, unsigned* __restrict__ Ghist) {
    __shared__ unsigned hist[P_PART];
    for (int i = threadIdx.x; i < P_PART; i += 256) hist[i] = 0;
    __syncthreads();
    const int chunk = (E_TOT + B1 - 1) / B1;
    const int beg = blockIdx.x * chunk;
    const int end = min(beg + chunk, E_TOT);
    for (int i = beg + threadIdx.x; i < end; i += 256) {
        int d = (i < E_EDGES) ? edst[i] : (i - E_EDGES);
        atomicAdd(&hist[d >> 8], 1u);          // LDS atomic
    }
    __syncthreads();
    for (int p = threadIdx.x; p < P_PART; p += 256)
        Ghist[p * B1 + blockIdx.x] = hist[p];  // bin-major for scan
}

// Pass 2: single-workgroup exclusive scan over 50176 (bin,block) counts.
__global__ void scan2_kernel(const unsigned* __restrict__ Ghist, unsigned* __restrict__ Goff) {
    __shared__ unsigned lds[1024];
    const int t = threadIdx.x;
    const int C = (NSCAN + 1023) / 1024;
    const int beg = t * C;
    const int end = min(beg + C, NSCAN);
    unsigned sum = 0;
    for (int i = beg; i < end; ++i) sum += Ghist[i];
    lds[t] = sum;
    __syncthreads();
    for (int off = 1; off < 1024; off <<= 1) {
        unsigned x = (t >= off) ? lds[t - off] : 0;
        __syncthreads();
        lds[t] += x;
        __syncthreads();
    }
    unsigned run = (t == 0) ? 0 : lds[t - 1];
    for (int i = beg; i < end; ++i) { Goff[i] = run; run += Ghist[i]; }
}

// partition bases + ptr[N] sentinel (separate kernel for global visibility)
__global__ void partbase_kernel(const unsigned* __restrict__ Goff,
                                int* __restrict__ partbase, int* __restrict__ ptr) {
    int p = threadIdx.x;
    if (p < P_PART) partbase[p] = (int)Goff[p * B1];
    if (p == P_PART) partbase[P_PART] = E_TOT;
    if (p == 0) ptr[N_NODES] = E_TOT;
}

// Pass 3: scatter edges into partition-sorted buffer; each (block,bin)
// slice is exclusive by the scan -> no cross-XCD line bouncing.
__global__ void scat2_kernel(const int* __restrict__ esrc, const int* __restrict__ edst,
                             const unsigned* __restrict__ Goff, unsigned* __restrict__ Gpart) {
    __shared__ unsigned cur[P_PART];
    for (int p = threadIdx.x; p < P_PART; p += 256) cur[p] = Goff[p * B1 + blockIdx.x];
    __syncthreads();
    const int chunk = (E_TOT + B1 - 1) / B1;
    const int beg = blockIdx.x * chunk;
    const int end = min(beg + chunk, E_TOT);
    for (int i = beg + threadIdx.x; i < end; i += 256) {
        int s = (i < E_EDGES) ? esrc[i] : (i - E_EDGES);
        int d = (i < E_EDGES) ? edst[i] : (i - E_EDGES);
        unsigned slot = atomicAdd(&cur[d >> 8], 1u);   // LDS atomic
        Gpart[slot] = ((unsigned)(d & 255) << 16) | (unsigned)s;
    }
}

// Pass 4: one block per partition: LDS deg count -> LDS scan -> ptr +
// csr scatter into the block-owned contiguous region. All atomics LDS.
__global__ void csr_kernel(const int* __restrict__ partbase, const unsigned* __restrict__ Gpart,
                           int* __restrict__ ptr, unsigned short* __restrict__ csr) {
    __shared__ unsigned deg[256];
    __shared__ unsigned scn[256];
    const int p = blockIdx.x;
    const int t = threadIdx.x;
    const int base = partbase[p];
    const int cnt = partbase[p + 1] - base;
    deg[t] = 0;
    __syncthreads();
    for (int i = t; i < cnt; i += 256)
        atomicAdd(&deg[Gpart[base + i] >> 16], 1u);
    __syncthreads();
    unsigned v = deg[t];
    scn[t] = v;
    __syncthreads();
    for (int o = 1; o < 256; o <<= 1) {
        unsigned x = (t >= o) ? scn[t - o] : 0;
        __syncthreads();
        scn[t] += x;
        __syncthreads();
    }
    unsigned excl = scn[t] - v;           // exclusive prefix
    int node = p * 256 + t;
    if (node < N_NODES) ptr[node] = base + (int)excl;
    __syncthreads();
    deg[t] = excl;                        // reuse deg[] as cursor
    __syncthreads();
    for (int i = t; i < cnt; i += 256) {
        unsigned rec = Gpart[base + i];
        unsigned slot = atomicAdd(&deg[rec >> 16], 1u);   // LDS atomic
        csr[base + slot] = (unsigned short)(rec & 0xFFFFu);
    }
}

// ==================== h = x @ W  (+ attention coefficients) ==============
template<int K>
__global__ void lin_att_kernel(const float* __restrict__ x,
                               const float* __restrict__ W,
                               const float* __restrict__ a_s,
                               const float* __restrict__ a_d,
                               __hip_bfloat16* __restrict__ h,
                               float* __restrict__ asrc,
                               float* __restrict__ adst,
                               int n) {
    __shared__ float sW[K * 64];
    const int tid = threadIdx.x, lane = tid & 63;
    for (int i = tid; i < K * 64; i += 256) sW[i] = W[i];
    __syncthreads();
    const float a_sv = a_s[lane];
    const float a_dv = a_d[lane];
    const int wid = blockIdx.x * 4 + (tid >> 6);
    const int nwaves = gridDim.x * 4;
    for (int node = wid; node < n; node += nwaves) {
        float xr[K / 64];
        #pragma unroll
        for (int p = 0; p < K / 64; ++p) xr[p] = x[node * K + p * 64 + lane];
        float acc = 0.f;
        #pragma unroll
        for (int p = 0; p < K / 64; ++p) {
            #pragma unroll
            for (int k = 0; k < 64; ++k) {
                float xk = rl_f(xr[p], k);
                acc = fmaf(xk, sW[(p * 64 + k) * 64 + lane], acc);
            }
        }
        h[node * 64 + lane] = __float2bfloat16(acc);
        float ps = acc * a_sv, pd = acc * a_dv;
        #pragma unroll
        for (int m = 1; m < 32; m <<= 1) {
            ps += __shfl_xor(ps, m, 64);
            pd += __shfl_xor(pd, m, 64);
        }
        if ((lane & 31) == 0) {
            asrc[node * 2 + (lane >> 5)] = ps;
            adst[node * 2 + (lane >> 5)] = pd;
        }
    }
}

// ==================== fused GAT aggregate: chunked flash-style ===========
template<bool BN, bool FINAL>
__global__ void gat_agg_kernel(const int* __restrict__ ptr,
                               const unsigned short* __restrict__ csr_src,
                               const __hip_bfloat16* __restrict__ h,
                               const float2* __restrict__ asrc, const float2* __restrict__ adst,
                               const float* __restrict__ bias,
                               const float* __restrict__ gamma, const float* __restrict__ beta,
                               const float* __restrict__ mean, const float* __restrict__ var,
                               float* __restrict__ out,
                               const float* __restrict__ x1, const float* __restrict__ Wf,
                               const float* __restrict__ bf, float* __restrict__ out40) {
    __shared__ float sWf[FINAL ? 64 * 40 : 1];
    if constexpr (FINAL) {
        for (int i = threadIdx.x; i < 64 * 40; i += 256) sWf[i] = Wf[i];
        __syncthreads();
    }
    int node = blockIdx.x * 4 + (threadIdx.x >> 6);
    if (node >= N_NODES) return;
    const int lane = threadIdx.x & 63;
    const int half = lane & 31;
    float2 ad = adst[node];
    const float adh = (lane < 32) ? ad.x : ad.y;
    float m = -INFINITY, s = 0.f, acc = 0.f;
    const int beg = ptr[node], end = ptr[node + 1];
    for (int base = beg; base < end; base += 32) {
        const int cnt = min(32, end - base);
        int src = 0; float ev = -INFINITY;
        if (half < cnt) {
            src = (int)csr_src[base + half];
            float2 a2 = asrc[src];
            ev = ((lane < 32) ? a2.x : a2.y) + adh;
            ev = ev > 0.f ? ev : NEG_SLOPE * ev;
        }
        float cmax = ev;
        #pragma unroll
        for (int o = 1; o < 32; o <<= 1) cmax = fmaxf(cmax, __shfl_xor(cmax, o, 64));
        const float mn = fmaxf(m, cmax);
        const float rescale = __expf(m - mn);
        const float w = (half < cnt) ? __expf(ev - mn) : 0.f;
        float ws = w;
        #pragma unroll
        for (int o = 1; o < 32; o <<= 1) ws += __shfl_xor(ws, o, 64);
        s = s * rescale + ws;
        acc *= rescale;
        m = mn;
        int j = 0;
        for (; j + 4 <= cnt; j += 4) {
            int s0 = rl_i(src, j);
            int s1 = rl_i(src, j + 1);
            int s2 = rl_i(src, j + 2);
            int s3 = rl_i(src, j + 3);
            float wa0 = rl_f(w, j),      wb0 = rl_f(w, j + 32);
            float wa1 = rl_f(w, j + 1),  wb1 = rl_f(w, j + 33);
            float wa2 = rl_f(w, j + 2),  wb2 = rl_f(w, j + 34);
            float wa3 = rl_f(w, j + 3),  wb3 = rl_f(w, j + 35);
            float w0 = (lane < 32) ? wa0 : wb0;
            float w1 = (lane < 32) ? wa1 : wb1;
            float w2 = (lane < 32) ? wa2 : wb2;
            float w3 = (lane < 32) ? wa3 : wb3;
            float h0 = __bfloat162float(h[s0 * 64 + lane]);
            float h1 = __bfloat162float(h[s1 * 64 + lane]);
            float h2 = __bfloat162float(h[s2 * 64 + lane]);
            float h3 = __bfloat162float(h[s3 * 64 + lane]);
            acc = fmaf(w0, h0, acc);
            acc = fmaf(w1, h1, acc);
            acc = fmaf(w2, h2, acc);
            acc = fmaf(w3, h3, acc);
        }
        for (; j < cnt; ++j) {
            int sj = rl_i(src, j);
            float wa = rl_f(w, j), wb = rl_f(w, j + 32);
            float wj = (lane < 32) ? wa : wb;
            acc = fmaf(wj, __bfloat162float(h[sj * 64 + lane]), acc);
        }
    }
    float v = acc / (s + 1e-16f) + bias[lane];
    if constexpr (BN) {
        v = (v - mean[lane]) * rsqrtf(var[lane] + BN_EPS) * gamma[lane] + beta[lane];
        v = v > 0.f ? v : (__expf(v) - 1.f);   // ELU
    }
    if constexpr (FINAL) {
        float jk = fmaxf(x1[node * 64 + lane], v);
        const int o = (lane < 40) ? lane : 0;
        float dot = 0.f;
        #pragma unroll
        for (int c = 0; c < 64; ++c) {
            float jv = rl_f(jk, c);
            dot = fmaf(jv, sWf[c * 40 + o], dot);
        }
        float logit = (lane < 40) ? (dot + bf[o]) : -INFINITY;
        float mx = logit;
        #pragma unroll
        for (int mm = 1; mm < 64; mm <<= 1) mx = fmaxf(mx, __shfl_xor(mx, mm, 64));
        float ex = (lane < 40) ? __expf(logit - mx) : 0.f;
        float sum = ex;
        #pragma unroll
        for (int mm = 1; mm < 64; mm <<= 1) sum += __shfl_xor(sum, mm, 64);
        if (lane < 40) out40[node * 40 + lane] = logit - mx - logf(sum);
    } else {
        out[node * 64 + lane] = v;
    }
}

extern "C" void kernel_launch(void* const* d_in, const int* in_sizes, int n_in,
                              void* d_out, int out_size, void* d_ws, size_t ws_size,
                              hipStream_t stream) {
    const float* x     = (const float*)d_in[0];
    const int*   ei    = (const int*)d_in[1];
    const float* W1    = (const float*)d_in[2];
    const float* as1   = (const float*)d_in[3];
    const float* ad1   = (const float*)d_in[4];
    const float* b1    = (const float*)d_in[5];
    const float* gamma = (const float*)d_in[6];
    const float* beta  = (const float*)d_in[7];
    const float* mean  = (const float*)d_in[8];
    const float* var   = (const float*)d_in[9];
    const float* W2    = (const float*)d_in[10];
    const float* as2   = (const float*)d_in[11];
    const float* ad2   = (const float*)d_in[12];
    const float* b2    = (const float*)d_in[13];
    const float* Wf    = (const float*)d_in[14];
    const float* bf    = (const float*)d_in[15];
    float* out = (float*)d_out;
    const int* esrc = ei;
    const int* edst = ei + E_EDGES;

    char* ws = (char*)d_ws;
    size_t off = 0;
    auto alloc = [&](size_t bytes) {
        char* p = ws + off;
        off += (bytes + 255) & ~(size_t)255;
        return p;
    };
    unsigned* Ghist = (unsigned*)alloc((size_t)NSCAN * 4);
    unsigned* Goff  = (unsigned*)alloc((size_t)NSCAN * 4);
    int* partbase   = (int*)alloc((size_t)(P_PART + 1) * 4);
    unsigned* Gpart = (unsigned*)alloc((size_t)E_TOT * 4);
    int* ptr             = (int*)alloc((size_t)(N_NODES + 1) * 4);
    unsigned short* csr  = (unsigned short*)alloc((size_t)E_TOT * 2);
    __hip_bfloat16* hbuf = (__hip_bfloat16*)alloc((size_t)N_NODES * 64 * 2);
    float* x1buf = (float*)alloc((size_t)N_NODES * 64 * 4);
    float* asrc  = (float*)alloc((size_t)N_NODES * 2 * 4);
    float* adst  = (float*)alloc((size_t)N_NODES * 2 * 4);
    (void)ws_size; (void)in_sizes; (void)n_in; (void)out_size;

    const int NB = (N_NODES + 3) / 4;

    // ---------- CSR build (atomic-free partition sort) ----------
    hist_kernel<<<B1, 256, 0, stream>>>(edst, Ghist);
    scan2_kernel<<<1, 1024, 0, stream>>>(Ghist, Goff);
    partbase_kernel<<<1, 256, 0, stream>>>(Goff, partbase, ptr);
    scat2_kernel<<<B1, 256, 0, stream>>>(esrc, edst, Goff, Gpart);
    csr_kernel<<<P_PART, 256, 0, stream>>>(partbase, Gpart, ptr, csr);

    // ---------- layer 1 ----------
    lin_att_kernel<128><<<2048, 256, 0, stream>>>(x, W1, as1, ad1, hbuf, asrc, adst, N_NODES);
    gat_agg_kernel<true, false><<<NB, 256, 0, stream>>>(ptr, csr, hbuf,
        (const float2*)asrc, (const float2*)adst,
        b1, gamma, beta, mean, var, x1buf, nullptr, nullptr, nullptr, nullptr);

    // ---------- layer 2 (+ fused JK + final linear + log_softmax) ----------
    lin_att_kernel<64><<<2048, 256, 0, stream>>>(x1buf, W2, as2, ad2, hbuf, asrc, adst, N_NODES);
    gat_agg_kernel<false, true><<<NB, 256, 0, stream>>>(ptr, csr, hbuf,
        (const float2*)asrc, (const float2*)adst,
        b2, nullptr, nullptr, nullptr, nullptr, nullptr, x1buf, Wf, bf, out);
}